// Round 5
// baseline (492.144 us; speedup 1.0000x reference)
//
#include <hip/hip_runtime.h>
#include <stdint.h>

// ---------- types & helpers ----------
typedef short bf16x8 __attribute__((ext_vector_type(8)));
typedef float f32x4 __attribute__((ext_vector_type(4)));

__device__ __forceinline__ uint16_t f2b(float f) {
    uint32_t u = __builtin_bit_cast(uint32_t, f);
    return (uint16_t)((u + 0x7fffu + ((u >> 16) & 1u)) >> 16);
}

__device__ __forceinline__ void gll16(const void* g, void* l) {
    __builtin_amdgcn_global_load_lds(
        (const __attribute__((address_space(1))) uint32_t*)(uintptr_t)g,
        (__attribute__((address_space(3))) uint32_t*)(uint32_t)(uintptr_t)l,
        16, 0, 0);
}

// ---------- fp32 -> bf16 convert (x) ----------
__global__ __launch_bounds__(256) void cvt_f32_bf16(const float4* __restrict__ in,
                                                    uint2* __restrict__ out, int nvec) {
    int i = blockIdx.x * 256 + threadIdx.x;
    if (i >= nvec) return;
    float4 v = in[i];
    uint2 o;
    o.x = (uint32_t)f2b(v.x) | ((uint32_t)f2b(v.y) << 16);
    o.y = (uint32_t)f2b(v.z) | ((uint32_t)f2b(v.w) << 16);
    out[i] = o;
}

// ---------- weight transpose: W[1024][1024] f32 -> Wt[m][e][d] bf16 ----------
struct Ptr4 { const float* p[4]; };

__global__ __launch_bounds__(256) void tr_w(Ptr4 wp, uint16_t* __restrict__ out) {
    const int m = blockIdx.z;
    const float* in = wp.p[m];
    uint16_t* o = out + (size_t)m * 1048576;
    __shared__ uint16_t tile[64][68];
    int t = threadIdx.x;
    int r0 = blockIdx.y * 64, c0 = blockIdx.x * 64;
    for (int p = 0; p < 4; p++) {
        int row = p * 16 + (t >> 4);
        int c4 = (t & 15) * 4;
        float4 v = *(const float4*)&in[(size_t)(r0 + row) * 1024 + c0 + c4];
        tile[row][c4 + 0] = f2b(v.x);
        tile[row][c4 + 1] = f2b(v.y);
        tile[row][c4 + 2] = f2b(v.z);
        tile[row][c4 + 3] = f2b(v.w);
    }
    __syncthreads();
    for (int p = 0; p < 4; p++) {
        int a = p * 16 + (t >> 4);
        int b4 = (t & 15) * 4;
        uint32_t x0 = tile[b4 + 0][a], x1 = tile[b4 + 1][a];
        uint32_t x2 = tile[b4 + 2][a], x3 = tile[b4 + 3][a];
        uint2 pk;
        pk.x = x0 | (x1 << 16);
        pk.y = x2 | (x3 << 16);
        *(uint2*)&o[(size_t)(c0 + a) * 1024 + r0 + b4] = pk;
    }
}

// ---------- fused dual-B projection, BK=64 ----------
// grid (16,128). bx<8: B1=QL^T,B2=QR^T slice for e-block bx*128 -> register gate -> Q.
// bx>=8: B1=K^T,B2=V^T for e-block (bx-8)*128 -> per-wave LDS transpose -> KT/VT.
// LDS staging layout per matrix: [2 khalf][128 rows][32 k]  (row stride 32 elts).
union SmemP {
    struct { uint16_t lA[8192]; uint16_t lB1[8192]; uint16_t lB2[8192]; } s;  // 48 KB
    uint16_t tr[4][64][68];                                                    // 34816 B
};

__global__ __launch_bounds__(256) void proj_dual(const uint16_t* __restrict__ A,
                                                 const uint16_t* __restrict__ Wt,
                                                 uint16_t* __restrict__ Q,
                                                 uint16_t* __restrict__ KT,
                                                 uint16_t* __restrict__ VT) {
    __shared__ SmemP u;
    const int t = threadIdx.x;
    const int wave = t >> 6;
    const int lane = t & 63;
    const int m0 = blockIdx.y * 128;
    const int bx = blockIdx.x;
    const int gate = bx < 8;
    const int e0 = (gate ? bx : bx - 8) * 128;
    const uint16_t* B1 = Wt + (size_t)(gate ? 0 : 2) * 1048576 + (size_t)e0 * 1024;
    const uint16_t* B2 = Wt + (size_t)(gate ? 1 : 3) * 1048576 + (size_t)e0 * 1024;
    const int wm = (wave >> 1) * 64;
    const int wn = (wave & 1) * 64;

    // staging: thread t covers rows t>>2, k-inner chunk t&3; 4 gll16 per matrix:
    // dest +{0,2048,4096,6144} elts <-> global +{0, 64*ld, 32, 64*ld+32}
    const uint16_t* gA = A + (size_t)(m0 + (t >> 2)) * 1024 + (t & 3) * 8;
    const uint16_t* gB1 = B1 + (size_t)(t >> 2) * 1024 + (t & 3) * 8;
    const uint16_t* gB2 = B2 + (size_t)(t >> 2) * 1024 + (t & 3) * 8;
    uint16_t* dA = u.s.lA + wave * 512;
    uint16_t* dB1 = u.s.lB1 + wave * 512;
    uint16_t* dB2 = u.s.lB2 + wave * 512;

    f32x4 acc1[4][4] = {};
    f32x4 acc2[4][4] = {};

    const int arow = wm + (lane & 15);
    const int brow = wn + (lane & 15);
    const int koff = (lane >> 4) * 8;

    for (int k0 = 0; k0 < 1024; k0 += 64) {
        __syncthreads();
        gll16(gA + k0, dA);
        gll16(gA + k0 + 65536, dA + 2048);
        gll16(gA + k0 + 32, dA + 4096);
        gll16(gA + k0 + 65568, dA + 6144);
        gll16(gB1 + k0, dB1);
        gll16(gB1 + k0 + 65536, dB1 + 2048);
        gll16(gB1 + k0 + 32, dB1 + 4096);
        gll16(gB1 + k0 + 65568, dB1 + 6144);
        gll16(gB2 + k0, dB2);
        gll16(gB2 + k0 + 65536, dB2 + 2048);
        gll16(gB2 + k0 + 32, dB2 + 4096);
        gll16(gB2 + k0 + 65568, dB2 + 6144);
        __syncthreads();

#pragma unroll
        for (int h = 0; h < 2; h++) {
            const uint16_t* pA = u.s.lA + h * 4096;
            const uint16_t* pB1 = u.s.lB1 + h * 4096;
            const uint16_t* pB2 = u.s.lB2 + h * 4096;
            bf16x8 af[4], b1f[4], b2f[4];
#pragma unroll
            for (int i = 0; i < 4; i++)
                af[i] = *(const bf16x8*)&pA[(arow + i * 16) * 32 + koff];
#pragma unroll
            for (int i = 0; i < 4; i++)
                b1f[i] = *(const bf16x8*)&pB1[(brow + i * 16) * 32 + koff];
#pragma unroll
            for (int i = 0; i < 4; i++)
                b2f[i] = *(const bf16x8*)&pB2[(brow + i * 16) * 32 + koff];
#pragma unroll
            for (int i = 0; i < 4; i++)
#pragma unroll
                for (int j = 0; j < 4; j++) {
                    acc1[i][j] = __builtin_amdgcn_mfma_f32_16x16x32_bf16(af[i], b1f[j],
                                                                         acc1[i][j], 0, 0, 0);
                    acc2[i][j] = __builtin_amdgcn_mfma_f32_16x16x32_bf16(af[i], b2f[j],
                                                                         acc2[i][j], 0, 0, 0);
                }
        }
    }

    const int rl = (lane >> 4) * 4;
    const int cl = lane & 15;

    if (gate) {
        // register-only gate: Q = acc1 * acc2, same e's in both accs
#pragma unroll
        for (int i = 0; i < 4; i++)
#pragma unroll
            for (int j = 0; j < 4; j++)
#pragma unroll
                for (int r = 0; r < 4; r++) {
                    float g = acc1[i][j][r] * acc2[i][j][r];
                    Q[(size_t)(m0 + wm + i * 16 + rl + r) * 1024 + e0 + wn + j * 16 + cl] = f2b(g);
                }
    } else {
        // K/V transpose epilogue via per-wave LDS scratch
        __syncthreads();   // all waves done reading staging LDS before reuse
        const int batch = m0 >> 12;
        const int tok0 = (m0 & 4095) + wm;
        const int fbase = e0 + wn;
        uint16_t* outs[2] = {KT, VT};
        for (int s = 0; s < 2; s++) {
            f32x4(*acc)[4] = (s == 0) ? acc1 : acc2;
#pragma unroll
            for (int i = 0; i < 4; i++)
#pragma unroll
                for (int j = 0; j < 4; j++) {
                    int col = j * 16 + cl;
                    int row0 = i * 16 + rl;
                    uint2 pk;
                    pk.x = (uint32_t)f2b(acc[i][j][0]) | ((uint32_t)f2b(acc[i][j][1]) << 16);
                    pk.y = (uint32_t)f2b(acc[i][j][2]) | ((uint32_t)f2b(acc[i][j][3]) << 16);
                    *(uint2*)&u.tr[wave][col][row0] = pk;
                }
            __builtin_amdgcn_s_waitcnt(0);
            uint16_t* O = outs[s] + (size_t)batch * 4194304;
#pragma unroll
            for (int dd = 0; dd < 16; dd++) {
                int f = dd * 4 + (lane >> 4);
                int t4 = cl * 4;
                uint2 v = *(const uint2*)&u.tr[wave][f][t4];
                *(uint2*)&O[(size_t)(fbase + f) * 4096 + tok0 + t4] = v;
            }
            __builtin_amdgcn_s_waitcnt(0);
        }
    }
}

// ---------- split-K(2) kv GEMM: P[z] = VT-slice @ KT-slice^T, fp32 partials ----------
__global__ __launch_bounds__(256) void gemm_kv_splitk(const uint16_t* __restrict__ VT,
                                                      const uint16_t* __restrict__ KT,
                                                      float* __restrict__ P) {
    const int z = blockIdx.z;
    const int batch = z >> 1, ks = z & 1;
    const uint16_t* Ab = VT + (size_t)batch * 4194304 + ks * 2048;
    const uint16_t* Bb = KT + (size_t)batch * 4194304 + ks * 2048;

    __shared__ uint16_t lA[4096];
    __shared__ uint16_t lB[4096];

    const int t = threadIdx.x;
    const int wave = t >> 6;
    const int lane = t & 63;
    const int m0 = blockIdx.y * 128;
    const int n0 = blockIdx.x * 128;
    const int wm = (wave >> 1) * 64;
    const int wn = (wave & 1) * 64;

    const uint16_t* gA0 = Ab + (size_t)(m0 + (t >> 2)) * 4096 + (t & 3) * 8;
    const uint16_t* gB0 = Bb + (size_t)(n0 + (t >> 2)) * 4096 + (t & 3) * 8;
    uint16_t* lA0 = lA + wave * 512;
    uint16_t* lA1 = lA + 2048 + wave * 512;
    uint16_t* lB0 = lB + wave * 512;
    uint16_t* lB1 = lB + 2048 + wave * 512;

    f32x4 acc[4][4] = {};

    const int arow = wm + (lane & 15);
    const int brow = wn + (lane & 15);
    const int koff = (lane >> 4) * 8;

    for (int k0 = 0; k0 < 2048; k0 += 32) {
        __syncthreads();
        gll16(gA0 + k0, lA0);
        gll16(gA0 + (size_t)64 * 4096 + k0, lA1);
        gll16(gB0 + k0, lB0);
        gll16(gB0 + (size_t)64 * 4096 + k0, lB1);
        __syncthreads();

        bf16x8 af[4], bfr[4];
#pragma unroll
        for (int i = 0; i < 4; i++)
            af[i] = *(const bf16x8*)&lA[(arow + i * 16) * 32 + koff];
#pragma unroll
        for (int i = 0; i < 4; i++)
            bfr[i] = *(const bf16x8*)&lB[(brow + i * 16) * 32 + koff];
#pragma unroll
        for (int i = 0; i < 4; i++)
#pragma unroll
            for (int j = 0; j < 4; j++)
                acc[i][j] = __builtin_amdgcn_mfma_f32_16x16x32_bf16(af[i], bfr[j],
                                                                    acc[i][j], 0, 0, 0);
    }

    float* Pb = P + (size_t)z * 1048576;
    const int crow = m0 + wm + (lane >> 4) * 4;
    const int ccol = n0 + wn + (lane & 15);
#pragma unroll
    for (int i = 0; i < 4; i++)
#pragma unroll
        for (int j = 0; j < 4; j++)
#pragma unroll
            for (int r = 0; r < 4; r++)
                Pb[(size_t)(crow + i * 16 + r) * 1024 + ccol + j * 16] = acc[i][j][r];
}

// ---------- reduce 2 fp32 partials -> bf16 kvT ----------
__global__ __launch_bounds__(256) void reduce_kv(const float4* __restrict__ P,
                                                 uint2* __restrict__ kvT) {
    int i = blockIdx.x * 256 + threadIdx.x;
    int b = i >> 18;
    int r = i & 262143;
    const float4* base = P + (size_t)b * 524288 + r;
    float4 s0 = base[0];
    float4 s1 = base[262144];
    float x = s0.x + s1.x;
    float y = s0.y + s1.y;
    float zz = s0.z + s1.z;
    float w = s0.w + s1.w;
    uint2 o;
    o.x = (uint32_t)f2b(x) | ((uint32_t)f2b(y) << 16);
    o.y = (uint32_t)f2b(zz) | ((uint32_t)f2b(w) << 16);
    kvT[i] = o;
}

// ---------- out GEMM: out[b][n][e] = Q @ kvT^T, fp32 out ----------
__global__ __launch_bounds__(256) void gemm_out(const uint16_t* __restrict__ A,
                                                const uint16_t* __restrict__ Bt,
                                                float* __restrict__ C) {
    const uint16_t* Ab = A + (size_t)blockIdx.z * 4194304;
    const uint16_t* Bb = Bt + (size_t)blockIdx.z * 1048576;

    __shared__ uint16_t lA[4096];
    __shared__ uint16_t lB[4096];

    const int t = threadIdx.x;
    const int wave = t >> 6;
    const int lane = t & 63;
    const int m0 = blockIdx.y * 128;
    const int n0 = blockIdx.x * 128;
    const int wm = (wave >> 1) * 64;
    const int wn = (wave & 1) * 64;

    const uint16_t* gA0 = Ab + (size_t)(m0 + (t >> 2)) * 1024 + (t & 3) * 8;
    const uint16_t* gB0 = Bb + (size_t)(n0 + (t >> 2)) * 1024 + (t & 3) * 8;
    uint16_t* lA0 = lA + wave * 512;
    uint16_t* lA1 = lA + 2048 + wave * 512;
    uint16_t* lB0 = lB + wave * 512;
    uint16_t* lB1 = lB + 2048 + wave * 512;

    f32x4 acc[4][4] = {};

    const int arow = wm + (lane & 15);
    const int brow = wn + (lane & 15);
    const int koff = (lane >> 4) * 8;

    for (int k0 = 0; k0 < 1024; k0 += 32) {
        __syncthreads();
        gll16(gA0 + k0, lA0);
        gll16(gA0 + (size_t)64 * 1024 + k0, lA1);
        gll16(gB0 + k0, lB0);
        gll16(gB0 + (size_t)64 * 1024 + k0, lB1);
        __syncthreads();

        bf16x8 af[4], bfr[4];
#pragma unroll
        for (int i = 0; i < 4; i++)
            af[i] = *(const bf16x8*)&lA[(arow + i * 16) * 32 + koff];
#pragma unroll
        for (int i = 0; i < 4; i++)
            bfr[i] = *(const bf16x8*)&lB[(brow + i * 16) * 32 + koff];
#pragma unroll
        for (int i = 0; i < 4; i++)
#pragma unroll
            for (int j = 0; j < 4; j++)
                acc[i][j] = __builtin_amdgcn_mfma_f32_16x16x32_bf16(af[i], bfr[j],
                                                                    acc[i][j], 0, 0, 0);
    }

    float* Cb = C + (size_t)blockIdx.z * 4194304;
    const int crow = m0 + wm + (lane >> 4) * 4;
    const int ccol = n0 + wn + (lane & 15);
#pragma unroll
    for (int i = 0; i < 4; i++)
#pragma unroll
        for (int j = 0; j < 4; j++)
#pragma unroll
            for (int r = 0; r < 4; r++)
                Cb[(size_t)(crow + i * 16 + r) * 1024 + ccol + j * 16] = acc[i][j][r];
}

// ---------- launch ----------
extern "C" void kernel_launch(void* const* d_in, const int* in_sizes, int n_in,
                              void* d_out, int out_size, void* d_ws, size_t ws_size,
                              hipStream_t stream) {
    const float* x = (const float*)d_in[0];

    uint16_t* ws = (uint16_t*)d_ws;
    uint16_t* xb  = ws;                        // [0, 32MB); dead after proj
    float*    kvP = (float*)d_ws;              // [0, 32MB) fp32 partials (after proj)
    uint16_t* Wt  = ws + 33554432;             // [64MB, 72MB) weights W^T x4
    uint16_t* kvT = Wt;                        // reuse after proj
    uint16_t* Q   = ws + 37748736;             // [72MB, 104MB)
    uint16_t* KT  = ws + 54525952;             // [104MB, 136MB)
    uint16_t* VT  = ws + 71303168;             // [136MB, 168MB)

    // 1. x -> bf16
    cvt_f32_bf16<<<16384, 256, 0, stream>>>((const float4*)x, (uint2*)xb, 4194304);

    // 2. weights -> W^T bf16 (ql, qr, k, v)
    Ptr4 wp;
    wp.p[0] = (const float*)d_in[1];
    wp.p[1] = (const float*)d_in[2];
    wp.p[2] = (const float*)d_in[3];
    wp.p[3] = (const float*)d_in[4];
    tr_w<<<dim3(16, 16, 4), 256, 0, stream>>>(wp, Wt);

    // 3. all projections (dual-B, BK=64): gate -> Q; K/V -> KT/VT transposed
    proj_dual<<<dim3(16, 128), 256, 0, stream>>>(xb, Wt, Q, KT, VT);

    // 4. kv partials (split-K = 2)
    gemm_kv_splitk<<<dim3(8, 8, 8), 256, 0, stream>>>(VT, KT, kvP);

    // 5. reduce partials -> kvT bf16
    reduce_kv<<<4096, 256, 0, stream>>>((const float4*)kvP, (uint2*)kvT);

    // 6. out = Q @ kvT^T, fp32
    gemm_out<<<dim3(8, 32, 4), 256, 0, stream>>>(Q, kvT, (float*)d_out);
}

// Round 6
// 391.232 us; speedup vs baseline: 1.2579x; 1.2579x over previous
//
#include <hip/hip_runtime.h>
#include <stdint.h>

// ---------- types & helpers ----------
typedef short bf16x8 __attribute__((ext_vector_type(8)));
typedef float f32x4 __attribute__((ext_vector_type(4)));

__device__ __forceinline__ uint16_t f2b(float f) {
    uint32_t u = __builtin_bit_cast(uint32_t, f);
    return (uint16_t)((u + 0x7fffu + ((u >> 16) & 1u)) >> 16);
}

__device__ __forceinline__ void gll16(const void* g, void* l) {
    __builtin_amdgcn_global_load_lds(
        (const __attribute__((address_space(1))) uint32_t*)(uintptr_t)g,
        (__attribute__((address_space(3))) uint32_t*)(uint32_t)(uintptr_t)l,
        16, 0, 0);
}

// ---------- fp32 -> bf16 convert (x) ----------
__global__ __launch_bounds__(256) void cvt_f32_bf16(const float4* __restrict__ in,
                                                    uint2* __restrict__ out, int nvec) {
    int i = blockIdx.x * 256 + threadIdx.x;
    if (i >= nvec) return;
    float4 v = in[i];
    uint2 o;
    o.x = (uint32_t)f2b(v.x) | ((uint32_t)f2b(v.y) << 16);
    o.y = (uint32_t)f2b(v.z) | ((uint32_t)f2b(v.w) << 16);
    out[i] = o;
}

// ---------- weight transpose: W[1024][1024] f32 -> Wt[m][e][d] bf16 ----------
struct Ptr4 { const float* p[4]; };

__global__ __launch_bounds__(256) void tr_w(Ptr4 wp, uint16_t* __restrict__ out) {
    const int m = blockIdx.z;
    const float* in = wp.p[m];
    uint16_t* o = out + (size_t)m * 1048576;
    __shared__ uint16_t tile[64][68];
    int t = threadIdx.x;
    int r0 = blockIdx.y * 64, c0 = blockIdx.x * 64;
    for (int p = 0; p < 4; p++) {
        int row = p * 16 + (t >> 4);
        int c4 = (t & 15) * 4;
        float4 v = *(const float4*)&in[(size_t)(r0 + row) * 1024 + c0 + c4];
        tile[row][c4 + 0] = f2b(v.x);
        tile[row][c4 + 1] = f2b(v.y);
        tile[row][c4 + 2] = f2b(v.z);
        tile[row][c4 + 3] = f2b(v.w);
    }
    __syncthreads();
    for (int p = 0; p < 4; p++) {
        int a = p * 16 + (t >> 4);
        int b4 = (t & 15) * 4;
        uint32_t x0 = tile[b4 + 0][a], x1 = tile[b4 + 1][a];
        uint32_t x2 = tile[b4 + 2][a], x3 = tile[b4 + 3][a];
        uint2 pk;
        pk.x = x0 | (x1 << 16);
        pk.y = x2 | (x3 << 16);
        *(uint2*)&o[(size_t)(c0 + a) * 1024 + r0 + b4] = pk;
    }
}

// ---------- fused dual-B projection: 512 threads, wave tile 64x32, BK=32 ----------
// grid (16,128). bx<8: B1=QL^T,B2=QR^T for e-block bx*128 -> register gate -> Q.
// bx>=8: B1=K^T,B2=V^T -> per-wave LDS transpose -> KT/VT [b][e][tok].
// Per-wave acc = 2*(4x2)*4 = 64 regs; target <=128 total for 4 waves/SIMD.
union SmemP {
    struct { uint16_t lA[4096]; uint16_t lB1[4096]; uint16_t lB2[4096]; } s;  // 24 KB
    uint16_t tr[8][32][68];                                                    // 34816 B
};

__global__ __launch_bounds__(512, 4) void proj512(const uint16_t* __restrict__ A,
                                                  const uint16_t* __restrict__ Wt,
                                                  uint16_t* __restrict__ Q,
                                                  uint16_t* __restrict__ KT,
                                                  uint16_t* __restrict__ VT) {
    __shared__ SmemP u;
    const int t = threadIdx.x;
    const int wave = t >> 6;
    const int lane = t & 63;
    const int m0 = blockIdx.y * 128;
    const int bx = blockIdx.x;
    const int gate = bx < 8;
    const int e0 = (gate ? bx : bx - 8) * 128;
    const uint16_t* B1 = Wt + (size_t)(gate ? 0 : 2) * 1048576 + (size_t)e0 * 1024;
    const uint16_t* B2 = Wt + (size_t)(gate ? 1 : 3) * 1048576 + (size_t)e0 * 1024;
    const int wm = (wave >> 2) * 64;     // 2 m-halves
    const int we = (wave & 3) * 32;      // 4 e-strips

    // staging: 512 threads cover one full 128x32 tile per matrix -> 1 gll16 each
    const uint16_t* gA = A + (size_t)(m0 + (t >> 2)) * 1024 + (t & 3) * 8;
    const uint16_t* gB1 = B1 + (size_t)(t >> 2) * 1024 + (t & 3) * 8;
    const uint16_t* gB2 = B2 + (size_t)(t >> 2) * 1024 + (t & 3) * 8;
    uint16_t* dA = u.s.lA + wave * 512;     // wave-uniform base + lane*16B
    uint16_t* dB1 = u.s.lB1 + wave * 512;
    uint16_t* dB2 = u.s.lB2 + wave * 512;

    f32x4 acc1[4][2] = {};
    f32x4 acc2[4][2] = {};

    const int arow = wm + (lane & 15);
    const int brow = we + (lane & 15);
    const int koff = (lane >> 4) * 8;

    for (int k0 = 0; k0 < 1024; k0 += 32) {
        __syncthreads();
        gll16(gA + k0, dA);
        gll16(gB1 + k0, dB1);
        gll16(gB2 + k0, dB2);
        __syncthreads();

        bf16x8 af[4], b1f[2], b2f[2];
#pragma unroll
        for (int i = 0; i < 4; i++)
            af[i] = *(const bf16x8*)&u.s.lA[(arow + i * 16) * 32 + koff];
#pragma unroll
        for (int j = 0; j < 2; j++)
            b1f[j] = *(const bf16x8*)&u.s.lB1[(brow + j * 16) * 32 + koff];
#pragma unroll
        for (int j = 0; j < 2; j++)
            b2f[j] = *(const bf16x8*)&u.s.lB2[(brow + j * 16) * 32 + koff];
#pragma unroll
        for (int i = 0; i < 4; i++)
#pragma unroll
            for (int j = 0; j < 2; j++) {
                acc1[i][j] = __builtin_amdgcn_mfma_f32_16x16x32_bf16(af[i], b1f[j],
                                                                     acc1[i][j], 0, 0, 0);
                acc2[i][j] = __builtin_amdgcn_mfma_f32_16x16x32_bf16(af[i], b2f[j],
                                                                     acc2[i][j], 0, 0, 0);
            }
    }

    const int rl = (lane >> 4) * 4;
    const int cl = lane & 15;

    if (gate) {
        // register-only gate: same e's in acc1/acc2
#pragma unroll
        for (int i = 0; i < 4; i++)
#pragma unroll
            for (int j = 0; j < 2; j++)
#pragma unroll
                for (int r = 0; r < 4; r++) {
                    float g = acc1[i][j][r] * acc2[i][j][r];
                    Q[(size_t)(m0 + wm + i * 16 + rl + r) * 1024 + e0 + we + j * 16 + cl] = f2b(g);
                }
    } else {
        // K/V transpose epilogue via per-wave LDS scratch (two passes: K then V)
        __syncthreads();   // all waves done reading staging LDS before reuse
        const int batch = m0 >> 12;
        const int tok0 = (m0 & 4095) + wm;
        const int fbase = e0 + we;
        uint16_t* outs[2] = {KT, VT};
        for (int s = 0; s < 2; s++) {
            f32x4(*acc)[2] = (s == 0) ? acc1 : acc2;
#pragma unroll
            for (int i = 0; i < 4; i++)
#pragma unroll
                for (int j = 0; j < 2; j++) {
                    int col = j * 16 + cl;      // e-local 0..31
                    int row0 = i * 16 + rl;     // tok-local 0..63
                    uint2 pk;
                    pk.x = (uint32_t)f2b(acc[i][j][0]) | ((uint32_t)f2b(acc[i][j][1]) << 16);
                    pk.y = (uint32_t)f2b(acc[i][j][2]) | ((uint32_t)f2b(acc[i][j][3]) << 16);
                    *(uint2*)&u.tr[wave][col][row0] = pk;
                }
            __builtin_amdgcn_s_waitcnt(0);
            uint16_t* O = outs[s] + (size_t)batch * 4194304;
#pragma unroll
            for (int dd = 0; dd < 8; dd++) {
                int f = dd * 4 + (lane >> 4);   // e-local 0..31
                int t4 = cl * 4;                // tok-local 0..60
                uint2 v = *(const uint2*)&u.tr[wave][f][t4];
                *(uint2*)&O[(size_t)(fbase + f) * 4096 + tok0 + t4] = v;
            }
            __builtin_amdgcn_s_waitcnt(0);
        }
    }
}

// ---------- split-K(2) kv GEMM: P[z] = VT-slice @ KT-slice^T, fp32 partials ----------
__global__ __launch_bounds__(256) void gemm_kv_splitk(const uint16_t* __restrict__ VT,
                                                      const uint16_t* __restrict__ KT,
                                                      float* __restrict__ P) {
    const int z = blockIdx.z;
    const int batch = z >> 1, ks = z & 1;
    const uint16_t* Ab = VT + (size_t)batch * 4194304 + ks * 2048;
    const uint16_t* Bb = KT + (size_t)batch * 4194304 + ks * 2048;

    __shared__ uint16_t lA[4096];
    __shared__ uint16_t lB[4096];

    const int t = threadIdx.x;
    const int wave = t >> 6;
    const int lane = t & 63;
    const int m0 = blockIdx.y * 128;
    const int n0 = blockIdx.x * 128;
    const int wm = (wave >> 1) * 64;
    const int wn = (wave & 1) * 64;

    const uint16_t* gA0 = Ab + (size_t)(m0 + (t >> 2)) * 4096 + (t & 3) * 8;
    const uint16_t* gB0 = Bb + (size_t)(n0 + (t >> 2)) * 4096 + (t & 3) * 8;
    uint16_t* lA0 = lA + wave * 512;
    uint16_t* lA1 = lA + 2048 + wave * 512;
    uint16_t* lB0 = lB + wave * 512;
    uint16_t* lB1 = lB + 2048 + wave * 512;

    f32x4 acc[4][4] = {};

    const int arow = wm + (lane & 15);
    const int brow = wn + (lane & 15);
    const int koff = (lane >> 4) * 8;

    for (int k0 = 0; k0 < 2048; k0 += 32) {
        __syncthreads();
        gll16(gA0 + k0, lA0);
        gll16(gA0 + (size_t)64 * 4096 + k0, lA1);
        gll16(gB0 + k0, lB0);
        gll16(gB0 + (size_t)64 * 4096 + k0, lB1);
        __syncthreads();

        bf16x8 af[4], bfr[4];
#pragma unroll
        for (int i = 0; i < 4; i++)
            af[i] = *(const bf16x8*)&lA[(arow + i * 16) * 32 + koff];
#pragma unroll
        for (int i = 0; i < 4; i++)
            bfr[i] = *(const bf16x8*)&lB[(brow + i * 16) * 32 + koff];
#pragma unroll
        for (int i = 0; i < 4; i++)
#pragma unroll
            for (int j = 0; j < 4; j++)
                acc[i][j] = __builtin_amdgcn_mfma_f32_16x16x32_bf16(af[i], bfr[j],
                                                                    acc[i][j], 0, 0, 0);
    }

    float* Pb = P + (size_t)z * 1048576;
    const int crow = m0 + wm + (lane >> 4) * 4;
    const int ccol = n0 + wn + (lane & 15);
#pragma unroll
    for (int i = 0; i < 4; i++)
#pragma unroll
        for (int j = 0; j < 4; j++)
#pragma unroll
            for (int r = 0; r < 4; r++)
                Pb[(size_t)(crow + i * 16 + r) * 1024 + ccol + j * 16] = acc[i][j][r];
}

// ---------- reduce 2 fp32 partials -> bf16 kvT ----------
__global__ __launch_bounds__(256) void reduce_kv(const float4* __restrict__ P,
                                                 uint2* __restrict__ kvT) {
    int i = blockIdx.x * 256 + threadIdx.x;
    int b = i >> 18;
    int r = i & 262143;
    const float4* base = P + (size_t)b * 524288 + r;
    float4 s0 = base[0];
    float4 s1 = base[262144];
    float x = s0.x + s1.x;
    float y = s0.y + s1.y;
    float zz = s0.z + s1.z;
    float w = s0.w + s1.w;
    uint2 o;
    o.x = (uint32_t)f2b(x) | ((uint32_t)f2b(y) << 16);
    o.y = (uint32_t)f2b(zz) | ((uint32_t)f2b(w) << 16);
    kvT[i] = o;
}

// ---------- out GEMM: out[b][n][e] = Q @ kvT^T, fp32 out ----------
__global__ __launch_bounds__(256) void gemm_out(const uint16_t* __restrict__ A,
                                                const uint16_t* __restrict__ Bt,
                                                float* __restrict__ C) {
    const uint16_t* Ab = A + (size_t)blockIdx.z * 4194304;
    const uint16_t* Bb = Bt + (size_t)blockIdx.z * 1048576;

    __shared__ uint16_t lA[4096];
    __shared__ uint16_t lB[4096];

    const int t = threadIdx.x;
    const int wave = t >> 6;
    const int lane = t & 63;
    const int m0 = blockIdx.y * 128;
    const int n0 = blockIdx.x * 128;
    const int wm = (wave >> 1) * 64;
    const int wn = (wave & 1) * 64;

    const uint16_t* gA0 = Ab + (size_t)(m0 + (t >> 2)) * 1024 + (t & 3) * 8;
    const uint16_t* gB0 = Bb + (size_t)(n0 + (t >> 2)) * 1024 + (t & 3) * 8;
    uint16_t* lA0 = lA + wave * 512;
    uint16_t* lA1 = lA + 2048 + wave * 512;
    uint16_t* lB0 = lB + wave * 512;
    uint16_t* lB1 = lB + 2048 + wave * 512;

    f32x4 acc[4][4] = {};

    const int arow = wm + (lane & 15);
    const int brow = wn + (lane & 15);
    const int koff = (lane >> 4) * 8;

    for (int k0 = 0; k0 < 1024; k0 += 32) {
        __syncthreads();
        gll16(gA0 + k0, lA0);
        gll16(gA0 + (size_t)64 * 1024 + k0, lA1);
        gll16(gB0 + k0, lB0);
        gll16(gB0 + (size_t)64 * 1024 + k0, lB1);
        __syncthreads();

        bf16x8 af[4], bfr[4];
#pragma unroll
        for (int i = 0; i < 4; i++)
            af[i] = *(const bf16x8*)&lA[(arow + i * 16) * 32 + koff];
#pragma unroll
        for (int i = 0; i < 4; i++)
            bfr[i] = *(const bf16x8*)&lB[(brow + i * 16) * 32 + koff];
#pragma unroll
        for (int i = 0; i < 4; i++)
#pragma unroll
            for (int j = 0; j < 4; j++)
                acc[i][j] = __builtin_amdgcn_mfma_f32_16x16x32_bf16(af[i], bfr[j],
                                                                    acc[i][j], 0, 0, 0);
    }

    float* Cb = C + (size_t)blockIdx.z * 4194304;
    const int crow = m0 + wm + (lane >> 4) * 4;
    const int ccol = n0 + wn + (lane & 15);
#pragma unroll
    for (int i = 0; i < 4; i++)
#pragma unroll
        for (int j = 0; j < 4; j++)
#pragma unroll
            for (int r = 0; r < 4; r++)
                Cb[(size_t)(crow + i * 16 + r) * 1024 + ccol + j * 16] = acc[i][j][r];
}

// ---------- launch ----------
extern "C" void kernel_launch(void* const* d_in, const int* in_sizes, int n_in,
                              void* d_out, int out_size, void* d_ws, size_t ws_size,
                              hipStream_t stream) {
    const float* x = (const float*)d_in[0];

    uint16_t* ws = (uint16_t*)d_ws;
    uint16_t* xb  = ws;                        // [0, 32MB); dead after proj
    float*    kvP = (float*)d_ws;              // [0, 32MB) fp32 partials (after proj)
    uint16_t* Wt  = ws + 33554432;             // [64MB, 72MB) weights W^T x4
    uint16_t* kvT = Wt;                        // reuse after proj
    uint16_t* Q   = ws + 37748736;             // [72MB, 104MB)
    uint16_t* KT  = ws + 54525952;             // [104MB, 136MB)
    uint16_t* VT  = ws + 71303168;             // [136MB, 168MB)

    // 1. x -> bf16
    cvt_f32_bf16<<<16384, 256, 0, stream>>>((const float4*)x, (uint2*)xb, 4194304);

    // 2. weights -> W^T bf16 (ql, qr, k, v)
    Ptr4 wp;
    wp.p[0] = (const float*)d_in[1];
    wp.p[1] = (const float*)d_in[2];
    wp.p[2] = (const float*)d_in[3];
    wp.p[3] = (const float*)d_in[4];
    tr_w<<<dim3(16, 16, 4), 256, 0, stream>>>(wp, Wt);

    // 3. all projections: 512-thread blocks, dual-B, wave 64x32, BK=32
    proj512<<<dim3(16, 128), 512, 0, stream>>>(xb, Wt, Q, KT, VT);

    // 4. kv partials (split-K = 2)
    gemm_kv_splitk<<<dim3(8, 8, 8), 256, 0, stream>>>(VT, KT, kvP);

    // 5. reduce partials -> kvT bf16
    reduce_kv<<<4096, 256, 0, stream>>>((const float4*)kvP, (uint2*)kvT);

    // 6. out = Q @ kvT^T, fp32
    gemm_out<<<dim3(8, 32, 4), 256, 0, stream>>>(Q, kvT, (float*)d_out);
}